// Round 1
// baseline (35.998 us; speedup 1.0000x reference)
//
#include <hip/hip_runtime.h>
#include <math.h>

// BettingLoss: scalar loss over B=1048576 races, T=8 dogs.
// Inputs (float32, each B*T): predicted_probs, true_winners(one-hot),
// market_odds, gumbel_noise. Output: 1 float32 scalar.

constexpr int T = 8;
constexpr int NB = 1024;   // blocks in main kernel
constexpr int NT = 256;    // threads per block

// accumulator indices: 0=cnt, 1=sum(ce*valid), 2=sum(ce), 3=sum(soft_ep*valid),
// 4=sum(max_prob), 5=sum(entropy)
__global__ __launch_bounds__(NT) void betting_main(
    const float* __restrict__ pp, const float* __restrict__ tw,
    const float* __restrict__ mo, const float* __restrict__ gn,
    float* __restrict__ partials, int nraces) {
  int tid = blockIdx.x * blockDim.x + threadIdx.x;
  int stride = gridDim.x * blockDim.x;

  float acc[6] = {0.f, 0.f, 0.f, 0.f, 0.f, 0.f};

  for (int r = tid; r < nraces; r += stride) {
    const float4* pp4 = (const float4*)pp;
    const float4* tw4 = (const float4*)tw;
    const float4* mo4 = (const float4*)mo;
    const float4* gn4 = (const float4*)gn;
    float4 a0 = pp4[r * 2], a1 = pp4[r * 2 + 1];
    float4 b0 = tw4[r * 2], b1 = tw4[r * 2 + 1];
    float4 c0 = mo4[r * 2], c1 = mo4[r * 2 + 1];
    float4 d0 = gn4[r * 2], d1 = gn4[r * 2 + 1];

    float p[T] = {a0.x, a0.y, a0.z, a0.w, a1.x, a1.y, a1.z, a1.w};
    float w[T] = {b0.x, b0.y, b0.z, b0.w, b1.x, b1.y, b1.z, b1.w};
    float o[T] = {c0.x, c0.y, c0.z, c0.w, c1.x, c1.y, c1.z, c1.w};
    float g[T] = {d0.x, d0.y, d0.z, d0.w, d1.x, d1.y, d1.z, d1.w};

    // ---- validity ----
    bool anypos = false;
    float simp = 0.f;
#pragma unroll
    for (int t = 0; t < T; ++t) {
      anypos = anypos || (o[t] > 0.f);
      simp += 1.f / fmaxf(o[t], 1.01f);
    }
    bool valid = anypos && (simp >= 0.95f);
    float vf = valid ? 1.f : 0.f;

    // ---- expected profit per dog (masked) ----
    float ep[T];
#pragma unroll
    for (int t = 0; t < T; ++t)
      ep[t] = valid ? (o[t] * 1.1f * p[t] - 1.f) * (0.02f * 0.95f) : 0.f;

    // ---- gumbel-softmax selection: softmax(ep*100 + g*10) ----
    float z[T], zm = -INFINITY;
#pragma unroll
    for (int t = 0; t < T; ++t) {
      z[t] = ep[t] * 100.f + g[t] * 10.f;
      zm = fmaxf(zm, z[t]);
    }
    float s2 = 0.f, sp = 0.f;
#pragma unroll
    for (int t = 0; t < T; ++t) {
      float e = __expf(z[t] - zm);
      s2 += e;
      sp += e * ep[t];
    }
    float soft_ep = sp / s2;

    // ---- cross-entropy: probs treated as logits ----
    float m = -INFINITY;
#pragma unroll
    for (int t = 0; t < T; ++t) m = fmaxf(m, p[t]);
    float se = 0.f, plabel = 0.f;
#pragma unroll
    for (int t = 0; t < T; ++t) {
      se += __expf(p[t] - m);
      plabel += w[t] * p[t];  // one-hot exact
    }
    float ce = m + __logf(se) - plabel;

    // ---- entropy of predicted_probs ----
    float ent = 0.f;
#pragma unroll
    for (int t = 0; t < T; ++t) ent -= p[t] * __logf(p[t] + 1e-8f);

    acc[0] += vf;
    acc[1] += ce * vf;
    acc[2] += ce;
    acc[3] += soft_ep * vf;
    acc[4] += m;   // max prob (same max as log-softmax max)
    acc[5] += ent;
  }

  // ---- block reduction: wave shfl -> LDS -> partials ----
  __shared__ float red[NT / 64][6];
#pragma unroll
  for (int k = 0; k < 6; ++k) {
#pragma unroll
    for (int off = 32; off >= 1; off >>= 1) acc[k] += __shfl_down(acc[k], off);
  }
  int lane = threadIdx.x & 63, wave = threadIdx.x >> 6;
  if (lane == 0) {
#pragma unroll
    for (int k = 0; k < 6; ++k) red[wave][k] = acc[k];
  }
  __syncthreads();
  if (threadIdx.x == 0) {
#pragma unroll
    for (int k = 0; k < 6; ++k) {
      float s = 0.f;
      for (int wv = 0; wv < NT / 64; ++wv) s += red[wv][k];
      partials[k * gridDim.x + blockIdx.x] = s;  // SoA for coalesced finalize
    }
  }
}

__global__ __launch_bounds__(NT) void betting_final(
    const float* __restrict__ partials, int nb, float* __restrict__ out,
    double Bd) {
  __shared__ double red[NT / 64][6];
  double a[6] = {0, 0, 0, 0, 0, 0};
#pragma unroll
  for (int k = 0; k < 6; ++k)
    for (int i = threadIdx.x; i < nb; i += NT) a[k] += (double)partials[k * nb + i];
#pragma unroll
  for (int k = 0; k < 6; ++k) {
#pragma unroll
    for (int off = 32; off >= 1; off >>= 1) a[k] += __shfl_down(a[k], off);
  }
  int lane = threadIdx.x & 63, wave = threadIdx.x >> 6;
  if (lane == 0) {
#pragma unroll
    for (int k = 0; k < 6; ++k) red[wave][k] = a[k];
  }
  __syncthreads();
  if (threadIdx.x == 0) {
    double s[6];
#pragma unroll
    for (int k = 0; k < 6; ++k) {
      s[k] = 0.0;
      for (int wv = 0; wv < NT / 64; ++wv) s[k] += red[wv][k];
    }
    double cnt = s[0], Scev = s[1], Sce = s[2], Ssoft = s[3], Smax = s[4],
           Sent = s[5];
    double pred = (cnt > 0.0) ? Scev / fmax(cnt, 1.0) : Sce / Bd;
    double conf = -(Smax / Bd) * 0.1;
    double bet = (cnt > 0.0) ? -Ssoft / Bd : conf;
    double ent = Sent / Bd;
    double lam = fmin(0.5 + cnt / 10000.0 * 0.5, 1.0);
    out[0] = (float)(pred + lam * bet - 0.01 * ent);
  }
}

extern "C" void kernel_launch(void* const* d_in, const int* in_sizes, int n_in,
                              void* d_out, int out_size, void* d_ws,
                              size_t ws_size, hipStream_t stream) {
  const float* pp = (const float*)d_in[0];
  const float* tw = (const float*)d_in[1];
  const float* mo = (const float*)d_in[2];
  const float* gn = (const float*)d_in[3];
  float* out = (float*)d_out;
  float* partials = (float*)d_ws;  // 6 * NB floats = 24 KB

  int nraces = in_sizes[0] / T;

  betting_main<<<NB, NT, 0, stream>>>(pp, tw, mo, gn, partials, nraces);
  betting_final<<<1, NT, 0, stream>>>(partials, NB, out, (double)nraces);
}